// Round 1
// baseline (349.297 us; speedup 1.0000x reference)
//
#include <hip/hip_runtime.h>
#include <math.h>

// CRF log-likelihood, B=2048, T=80, L=128.
// Exp-domain forward algorithm: one block (128 threads, 2 waves) per batch row.
// E=exp(trans) held in registers (each thread: 2 columns x 64 rows of its wave's
// half), v (scaled alpha-exp) one element per lane, broadcast via v_readlane.

#define CRF_B 2048
#define CRF_T 80
#define CRF_L 128

__device__ __forceinline__ float lane_bcast(float v, int k) {
    return __int_as_float(__builtin_amdgcn_readlane(__float_as_int(v), k));
}

__global__ __launch_bounds__(128) void crf_fwd_kernel(
    const float* __restrict__ x,           // [B,T,L]
    const float* __restrict__ trans,       // [L,L]
    const float* __restrict__ start_trans, // [L]
    const float* __restrict__ end_trans,   // [L]
    const int*   __restrict__ y,           // [B,T]
    float* __restrict__ out)               // [B]
{
    const int b   = blockIdx.x;
    const int tid = threadIdx.x;
    const int l   = tid & 63;   // lane in wave
    const int h   = tid >> 6;   // wave id (0/1): covers i in [64h, 64h+64)
    const int j   = tid;        // this thread's output column (= 64h + l)

    __shared__ float buf[128];  // cross-wave partial-sum exchange
    __shared__ float red[8];    // small reductions

    // --- preload E = exp(trans) into registers ---
    // E2[k].x = exp(trans[64h+k][l]) (column l, rows of our half)
    // E2[k].y = exp(trans[64h+k][64+l]) (column 64+l)
    float2 E2[64];
    #pragma unroll
    for (int k = 0; k < 64; ++k) {
        const int i = (h << 6) + k;
        E2[k].x = __expf(trans[i * CRF_L + l]);
        E2[k].y = __expf(trans[i * CRF_L + 64 + l]);
    }
    const float st = start_trans[j];
    const float et = end_trans[j];

    // --- numerator: per-thread partials (trans-chain + boundary terms) ---
    const int* yb = y + b * CRF_T;
    float num = 0.f;
    if (tid < CRF_T - 1) {
        const int y0 = yb[tid];
        const int y1 = yb[tid + 1];
        num = trans[y0 * CRF_L + y1];
    }
    if (tid == 0) {
        num += start_trans[yb[0]] + end_trans[yb[CRF_T - 1]];
    }

    const float* xb = x + (size_t)b * CRF_T * CRF_L;

    float vreg = 0.f;  // v[64h + l] = exp(alpha[64h+l] - c), max-normalized
    float c    = 0.f;  // log-scale offset (uniform across block)

    for (int t = 0; t < CRF_T; ++t) {
        float w = 0.f;
        if (t > 0) {
            // phase 1: partial mat-vec over our wave's i-half, both columns
            float sx = 0.f, sy = 0.f;
            #pragma unroll
            for (int k = 0; k < 64; ++k) {
                const float vi = lane_bcast(vreg, k);  // v[64h + k]
                sx += vi * E2[k].x;
                sy += vi * E2[k].y;
            }
            // phase 2: cross-wave combine.
            // wave0 lane l: owns col l   -> has (i<64) part in sx, needs wave1.sx
            // wave1 lane l: owns col 64+l-> has (i>=64) part in sy, needs wave0.sy
            buf[tid] = h ? sx : sy;
            __syncthreads();
            w = h ? (buf[l] + sy) : (sx + buf[64 + l]);
        }

        const float xv = xb[t * CRF_L + j];
        const int   yt = yb[t];
        if (j == yt) num += xv;  // gold-path emission (exactly one thread hits)

        const float wp = (t == 0) ? __expf(st + xv) : w * __expf(xv);

        // phase 3: block-wide max for rescaling
        float m = wp;
        #pragma unroll
        for (int off = 32; off > 0; off >>= 1)
            m = fmaxf(m, __shfl_xor(m, off));
        if (l == 0) red[h] = m;
        __syncthreads();
        const float M = fmaxf(red[0], red[1]);
        __syncthreads();

        c += __logf(M);
        vreg = wp / M;
    }

    // --- finish: log_z = c + log(sum_j v[j]*exp(end[j])), out = num - log_z ---
    float sv = vreg * __expf(et);
    float sn = num;
    #pragma unroll
    for (int off = 32; off > 0; off >>= 1) {
        sv += __shfl_xor(sv, off);
        sn += __shfl_xor(sn, off);
    }
    if (l == 0) { red[2 + h] = sv; red[4 + h] = sn; }
    __syncthreads();
    if (tid == 0) {
        const float S   = red[2] + red[3];
        const float NUM = red[4] + red[5];
        out[b] = NUM - (c + __logf(S));
    }
}

extern "C" void kernel_launch(void* const* d_in, const int* in_sizes, int n_in,
                              void* d_out, int out_size, void* d_ws, size_t ws_size,
                              hipStream_t stream) {
    const float* x     = (const float*)d_in[0];
    const float* trans = (const float*)d_in[1];
    const float* st    = (const float*)d_in[2];
    const float* et    = (const float*)d_in[3];
    const int*   y     = (const int*)d_in[4];
    float* out = (float*)d_out;

    crf_fwd_kernel<<<CRF_B, 128, 0, stream>>>(x, trans, st, et, y, out);
}

// Round 2
// 178.857 us; speedup vs baseline: 1.9529x; 1.9529x over previous
//
#include <hip/hip_runtime.h>
#include <math.h>

// CRF log-likelihood, B=2048, T=80, L=128 — MFMA exp-domain forward.
// Block = 8 batch rows (padded to a 16-row MFMA tile by duplication),
// 256 blocks x 256 threads (4 waves). Per step: W = V·E via
// mfma_f32_16x16x32_bf16 (E bf16 in register B-frags), P = W*exp(x_t),
// V round-trips LDS (C-layout -> bf16 -> A-frags), renorm every 4 steps.

#define CRF_B 2048
#define CRF_T 80
#define CRF_L 128

typedef __attribute__((ext_vector_type(8))) short bf16x8_t;  // 8 bf16 = 4 VGPRs
typedef __attribute__((ext_vector_type(4))) float f32x4_t;

__device__ __forceinline__ short f2bf(float f) {
    // round-to-nearest-even fp32 -> bf16 (inputs are finite, >= 0)
    unsigned u = __float_as_uint(f);
    unsigned r = (u + 0x7FFF + ((u >> 16) & 1)) >> 16;
    return (short)r;
}

__global__ __launch_bounds__(256) void crf_mfma_kernel(
    const float* __restrict__ x,           // [B,T,L]
    const float* __restrict__ trans,       // [L,L]
    const float* __restrict__ start_trans, // [L]
    const float* __restrict__ end_trans,   // [L]
    const int*   __restrict__ y,           // [B,T]
    float* __restrict__ out)               // [B]
{
    const int b0   = blockIdx.x * 8;
    const int tid  = threadIdx.x;
    const int w    = tid >> 6;       // wave 0..3
    const int lane = tid & 63;
    const int quad = lane >> 4;
    const int n16  = lane & 15;

    __shared__ __attribute__((aligned(16))) short Vb[2][16][136]; // bf16 V, padded
    __shared__ __attribute__((aligned(16))) float maxbuf[16][4];  // [row][wave]
    __shared__ float numbuf[8];

    // ---------- numerator (gold-path score), 32 threads per batch row ----------
    {
        const int rr = tid >> 5, tt = tid & 31;
        const int bb = b0 + rr;
        const int* yb = y + bb * CRF_T;
        const float* xbn = x + (size_t)bb * CRF_T * CRF_L;
        float p = 0.f;
        for (int t = tt; t < CRF_T; t += 32) {
            const int yt = yb[t];
            p += xbn[t * CRF_L + yt];
            if (t + 1 < CRF_T) p += trans[yt * CRF_L + yb[t + 1]];
            else               p += end_trans[yt];
            if (t == 0)        p += start_trans[yt];
        }
        p += __shfl_xor(p, 1);  p += __shfl_xor(p, 2);  p += __shfl_xor(p, 4);
        p += __shfl_xor(p, 8);  p += __shfl_xor(p, 16);
        if (tt == 0) numbuf[rr] = p;
    }

    // ---------- preload E = exp(trans) as MFMA B-fragments (registers) ----------
    // B-frag layout (16x16x32): lane holds B[k][n], n = lane&15, k = quad*8 + j.
    bf16x8_t Bf[2][4];
    int   cols[2];
    float expend[2], stc[2];
    #pragma unroll
    for (int c2 = 0; c2 < 2; ++c2) {
        const int col = 32 * w + 16 * c2 + n16;
        cols[c2]   = col;
        expend[c2] = __expf(end_trans[col]);
        stc[c2]    = start_trans[col];
        #pragma unroll
        for (int kk = 0; kk < 4; ++kk) {
            union { bf16x8_t v; short s[8]; } u;
            #pragma unroll
            for (int j = 0; j < 8; ++j) {
                const int k = 32 * kk + quad * 8 + j;
                u.s[j] = f2bf(__expf(trans[k * CRF_L + col]));
            }
            Bf[c2][kk] = u.v;
        }
    }

    // x row base pointers: tile row r -> batch b0 + (r&7)  (rows 8-15 duplicate)
    const float* xrow[4];
    #pragma unroll
    for (int r = 0; r < 4; ++r)
        xrow[r] = x + (size_t)(b0 + ((quad * 4 + r) & 7)) * CRF_T * CRF_L;

    float crun[4] = {0.f, 0.f, 0.f, 0.f};  // per-row log-scale offset (gamma)
    float invM[4] = {1.f, 1.f, 1.f, 1.f};
    f32x4_t P[2];                           // current step values (C layout)

    float xa[2][4], xb[2][4];               // x ping-pong buffers
    #pragma unroll
    for (int c2 = 0; c2 < 2; ++c2)
    #pragma unroll
    for (int r = 0; r < 4; ++r)
        xa[c2][r] = xrow[r][cols[c2]];      // t = 0

    auto body = [&](int t, float (&xc)[2][4], float (&xn)[2][4]) {
        // prefetch next step's emissions
        if (t + 1 < CRF_T) {
            #pragma unroll
            for (int c2 = 0; c2 < 2; ++c2)
            #pragma unroll
            for (int r = 0; r < 4; ++r)
                xn[c2][r] = xrow[r][(t + 1) * CRF_L + cols[c2]];
        }
        const int cur = t & 1, prv = cur ^ 1;

        if (t == 0) {
            #pragma unroll
            for (int c2 = 0; c2 < 2; ++c2) {
                #pragma unroll
                for (int r = 0; r < 4; ++r)
                    P[c2][r] = __expf(stc[c2] + xc[c2][r]);
            }
        } else {
            // A-frags from LDS: A[m][k], m = n16, k = quad*8 + j (+32*kk)
            bf16x8_t Af[4];
            #pragma unroll
            for (int kk = 0; kk < 4; ++kk)
                Af[kk] = *(const bf16x8_t*)&Vb[prv][n16][32 * kk + quad * 8];
            #pragma unroll
            for (int c2 = 0; c2 < 2; ++c2) {
                f32x4_t acc = {0.f, 0.f, 0.f, 0.f};
                #pragma unroll
                for (int kk = 0; kk < 4; ++kk)
                    acc = __builtin_amdgcn_mfma_f32_16x16x32_bf16(Af[kk], Bf[c2][kk], acc, 0, 0, 0);
                #pragma unroll
                for (int r = 0; r < 4; ++r)
                    P[c2][r] = acc[r] * __expf(xc[c2][r]) * invM[r];
            }
        }

        const bool renorm = ((t & 3) == 3) && (t < CRF_T - 1);
        if (renorm) {
            // per-row max over this wave's 32 cols (reduce over n16 bits)
            #pragma unroll
            for (int r = 0; r < 4; ++r) {
                float m = fmaxf(P[0][r], P[1][r]);
                m = fmaxf(m, __shfl_xor(m, 1));
                m = fmaxf(m, __shfl_xor(m, 2));
                m = fmaxf(m, __shfl_xor(m, 4));
                m = fmaxf(m, __shfl_xor(m, 8));
                if (n16 == 0) maxbuf[quad * 4 + r][w] = m;
            }
        }

        // write V_t (bf16, C layout) to the other LDS buffer
        #pragma unroll
        for (int c2 = 0; c2 < 2; ++c2)
        #pragma unroll
        for (int r = 0; r < 4; ++r)
            Vb[cur][quad * 4 + r][cols[c2]] = f2bf(P[c2][r]);

        __syncthreads();

        if (renorm) {
            #pragma unroll
            for (int r = 0; r < 4; ++r) {
                const f32x4_t mb = *(const f32x4_t*)&maxbuf[quad * 4 + r][0];
                const float M = fmaxf(fmaxf(mb[0], mb[1]), fmaxf(mb[2], mb[3]));
                crun[r] += __logf(M);   // applied to P at step t+1 via invM
                invM[r]  = 1.f / M;
            }
        } else {
            #pragma unroll
            for (int r = 0; r < 4; ++r) invM[r] = 1.f;
        }
    };

    for (int t = 0; t < CRF_T; t += 2) {
        body(t,     xa, xb);
        body(t + 1, xb, xa);
    }

    // ---------- epilogue: log_z = crun + log(sum_c P[c]*exp(end[c])) ----------
    #pragma unroll
    for (int r = 0; r < 4; ++r) {
        float v = P[0][r] * expend[0] + P[1][r] * expend[1];
        v += __shfl_xor(v, 1); v += __shfl_xor(v, 2);
        v += __shfl_xor(v, 4); v += __shfl_xor(v, 8);
        if (n16 == 0) maxbuf[quad * 4 + r][w] = v;   // reuse as sum buffer
    }
    __syncthreads();
    if (w == 0 && n16 == 0 && quad < 2) {
        #pragma unroll
        for (int r = 0; r < 4; ++r) {
            const int row = quad * 4 + r;            // rows 0..7 are real
            const f32x4_t sb = *(const f32x4_t*)&maxbuf[row][0];
            const float S = sb[0] + sb[1] + sb[2] + sb[3];
            out[b0 + row] = numbuf[row] - (crun[r] + __logf(S));
        }
    }
}

extern "C" void kernel_launch(void* const* d_in, const int* in_sizes, int n_in,
                              void* d_out, int out_size, void* d_ws, size_t ws_size,
                              hipStream_t stream) {
    const float* x     = (const float*)d_in[0];
    const float* trans = (const float*)d_in[1];
    const float* st    = (const float*)d_in[2];
    const float* et    = (const float*)d_in[3];
    const int*   y     = (const int*)d_in[4];
    float* out = (float*)d_out;

    crf_mfma_kernel<<<CRF_B / 8, 256, 0, stream>>>(x, trans, st, et, y, out);
}

// Round 3
// 167.335 us; speedup vs baseline: 2.0874x; 1.0689x over previous
//
#include <hip/hip_runtime.h>
#include <math.h>

// CRF log-likelihood, B=2048, T=80, L=128 — MFMA exp-domain forward, v3.
// Block = 16 REAL batch rows (batch on the MFMA n/n16 dimension), 4 waves,
// wave w owns output states [32w,32w+32). Per step: D = E^T (reg A-frags)
// x V^T (LDS B-frags), P = D*exp(x)*invM, renorm every step with 1-step
// delayed per-row max (piggybacked on the single per-step barrier).

#define CRF_B 2048
#define CRF_T 80
#define CRF_L 128

typedef __attribute__((ext_vector_type(8))) short bf16x8_t;  // 8 bf16 = 4 VGPRs
typedef __attribute__((ext_vector_type(4))) float f32x4_t;

__device__ __forceinline__ int pack_bf16_trunc(float lo, float hi) {
    // two fp32 -> packed bf16x2 by truncation (1-2 VALU ops, no rounding chain)
    return (int)((__float_as_uint(lo) >> 16) | (__float_as_uint(hi) & 0xFFFF0000u));
}

__global__ __launch_bounds__(256) void crf_v3_kernel(
    const float* __restrict__ x,           // [B,T,L]
    const float* __restrict__ trans,       // [L,L]
    const float* __restrict__ start_trans, // [L]
    const float* __restrict__ end_trans,   // [L]
    const int*   __restrict__ y,           // [B,T]
    float* __restrict__ out)               // [B]
{
    const int tid  = threadIdx.x;
    const int w    = tid >> 6;     // wave 0..3: owns states [32w, 32w+32)
    const int lane = tid & 63;
    const int quad = lane >> 4;
    const int n16  = lane & 15;    // batch row within tile (REAL row)
    const int row0 = blockIdx.x * 16;

    // V (bf16, [batch][state]) double-buffered; stride 136 shorts (16B-aligned,
    // +8 pad breaks the power-of-2 bank stride)
    __shared__ __attribute__((aligned(16))) short Vb[2][16][136];
    __shared__ __attribute__((aligned(16))) float maxb[2][16][4]; // [buf][row][wave]
    __shared__ __attribute__((aligned(16))) float sumb[16][4];
    __shared__ float numb[16];

    // ---------------- numerator: 16 threads per batch row ----------------
    {
        const int rr = tid >> 4, tt = tid & 15;
        const int bb = row0 + rr;
        const int* yb = y + bb * CRF_T;
        const float* xbn = x + (size_t)bb * CRF_T * CRF_L;
        float p = 0.f;
        for (int t = tt; t < CRF_T; t += 16) {
            const int yt = yb[t];
            p += xbn[t * CRF_L + yt];
            p += (t + 1 < CRF_T) ? trans[yt * CRF_L + yb[t + 1]] : end_trans[yt];
            if (t == 0) p += start_trans[yt];
        }
        p += __shfl_xor(p, 1); p += __shfl_xor(p, 2);
        p += __shfl_xor(p, 4); p += __shfl_xor(p, 8);
        if (tt == 0) numb[rr] = p;
    }

    // ---------- A-frags: E^T in registers. A[m][k] = exp(trans[k][m]) ----------
    // 16x16x32 A layout: lane holds A[m = n16][k = 32kk + 8quad + j]
    bf16x8_t Af[2][4];
    #pragma unroll
    for (int mt = 0; mt < 2; ++mt) {
        const int m = 32 * w + 16 * mt + n16;  // global output state
        #pragma unroll
        for (int kk = 0; kk < 4; ++kk) {
            union { bf16x8_t v; short s[8]; } u;
            #pragma unroll
            for (int j = 0; j < 8; ++j) {
                const int k = 32 * kk + 8 * quad + j;  // input state
                const float e = __expf(trans[k * CRF_L + m]);
                u.s[j] = (short)(__float_as_uint(e) >> 16);
            }
            Af[mt][kk] = u.v;
        }
    }

    // per-lane x column: 4 consecutive states per m-tile -> float4 loads
    const int sc0 = 32 * w + 4 * quad;        // m-tile 0 state base
    const int sc1 = sc0 + 16;                 // m-tile 1 state base
    const float* xr = x + (size_t)(row0 + n16) * CRF_T * CRF_L;

    f32x4_t ex_end[2], st4[2];
    {
        const f32x4_t e0 = *(const f32x4_t*)&end_trans[sc0];
        const f32x4_t e1 = *(const f32x4_t*)&end_trans[sc1];
        #pragma unroll
        for (int r = 0; r < 4; ++r) {
            ex_end[0][r] = __expf(e0[r]);
            ex_end[1][r] = __expf(e1[r]);
        }
        st4[0] = *(const f32x4_t*)&start_trans[sc0];
        st4[1] = *(const f32x4_t*)&start_trans[sc1];
    }

    f32x4_t P[2];
    float invM = 1.f, crun = 0.f;
    f32x4_t xc[2], xn[2];
    xc[0] = *(const f32x4_t*)&xr[sc0];
    xc[1] = *(const f32x4_t*)&xr[sc1];

    for (int t = 0; t < CRF_T; ++t) {
        // prefetch next step's emissions (consumed next iteration)
        if (t + 1 < CRF_T) {
            xn[0] = *(const f32x4_t*)&xr[(t + 1) * CRF_L + sc0];
            xn[1] = *(const f32x4_t*)&xr[(t + 1) * CRF_L + sc1];
        }

        if (t == 0) {
            #pragma unroll
            for (int r = 0; r < 4; ++r) {
                P[0][r] = __expf(st4[0][r] + xc[0][r]);
                P[1][r] = __expf(st4[1][r] + xc[1][r]);
            }
        } else {
            // B-frags: V^T from LDS. B[k][n]: n = n16 (batch), k = 32kk+8quad+j
            const short* vrow = &Vb[(t - 1) & 1][n16][0];
            bf16x8_t Bf[4];
            #pragma unroll
            for (int kk = 0; kk < 4; ++kk)
                Bf[kk] = *(const bf16x8_t*)&vrow[32 * kk + 8 * quad];
            #pragma unroll
            for (int mt = 0; mt < 2; ++mt) {
                f32x4_t acc = {0.f, 0.f, 0.f, 0.f};
                #pragma unroll
                for (int kk = 0; kk < 4; ++kk)
                    acc = __builtin_amdgcn_mfma_f32_16x16x32_bf16(Af[mt][kk], Bf[kk], acc, 0, 0, 0);
                #pragma unroll
                for (int r = 0; r < 4; ++r)
                    P[mt][r] = acc[r] * __expf(xc[mt][r]) * invM;
            }
        }

        if (t < CRF_T - 1) {
            // per-row (per-n16) max over all 128 states: local 8 -> cross-quad
            float g = fmaxf(fmaxf(fmaxf(P[0][0], P[0][1]), fmaxf(P[0][2], P[0][3])),
                            fmaxf(fmaxf(P[1][0], P[1][1]), fmaxf(P[1][2], P[1][3])));
            g = fmaxf(g, __shfl_xor(g, 16));
            g = fmaxf(g, __shfl_xor(g, 32));
            if (lane < 16) maxb[t & 1][n16][w] = g;  // quad 0 lanes

            // write V_t (bf16 trunc) to the other buffer: states are consecutive
            short* dst = &Vb[t & 1][n16][0];
            const int d00 = pack_bf16_trunc(P[0][0], P[0][1]);
            const int d01 = pack_bf16_trunc(P[0][2], P[0][3]);
            const int d10 = pack_bf16_trunc(P[1][0], P[1][1]);
            const int d11 = pack_bf16_trunc(P[1][2], P[1][3]);
            *(int2*)&dst[sc0] = make_int2(d00, d01);
            *(int2*)&dst[sc1] = make_int2(d10, d11);

            __syncthreads();

            // delayed renorm: M_t applied at step t+1 as a multiply
            const f32x4_t mb = *(const f32x4_t*)&maxb[t & 1][n16][0];
            const float M = fmaxf(fmaxf(mb[0], mb[1]), fmaxf(mb[2], mb[3]));
            crun += __logf(M);
            invM = __builtin_amdgcn_rcpf(M);
        }

        xc[0] = xn[0];
        xc[1] = xn[1];
    }

    // ------------- epilogue: log_z = crun + log(sum_s P[s]*exp(end[s])) -------------
    float sv = 0.f;
    #pragma unroll
    for (int mt = 0; mt < 2; ++mt)
    #pragma unroll
    for (int r = 0; r < 4; ++r)
        sv += P[mt][r] * ex_end[mt][r];
    sv += __shfl_xor(sv, 16);
    sv += __shfl_xor(sv, 32);
    if (lane < 16) sumb[n16][w] = sv;
    __syncthreads();
    if (tid < 16) {
        const f32x4_t sb = *(const f32x4_t*)&sumb[tid][0];
        const float S = sb[0] + sb[1] + sb[2] + sb[3];
        out[row0 + tid] = numb[tid] - (crun + __logf(S));
    }
}

extern "C" void kernel_launch(void* const* d_in, const int* in_sizes, int n_in,
                              void* d_out, int out_size, void* d_ws, size_t ws_size,
                              hipStream_t stream) {
    const float* x     = (const float*)d_in[0];
    const float* trans = (const float*)d_in[1];
    const float* st    = (const float*)d_in[2];
    const float* et    = (const float*)d_in[3];
    const int*   y     = (const int*)d_in[4];
    float* out = (float*)d_out;

    crf_v3_kernel<<<CRF_B / 16, 256, 0, stream>>>(x, trans, st, et, y, out);
}